// Round 2
// baseline (1129.928 us; speedup 1.0000x reference)
//
#include <hip/hip_runtime.h>
#include <stdint.h>

typedef __bf16 bf16;
typedef __attribute__((ext_vector_type(8))) __bf16 bf16x8;
typedef __attribute__((ext_vector_type(4))) float f32x4;
typedef unsigned short u16;
typedef unsigned int u32;

#define B_TOK 4096
#define D_IN  1024
#define D_HID 4096
#define D_OUT 1024
#define NE    8
#define KTOT  (NE * D_HID)   // 32768

// fp32 -> bf16 round-to-nearest-even
__device__ __forceinline__ u16 f2bf(float f) {
  u32 u = __float_as_uint(f);
  return (u16)((u + 0x7FFFu + ((u >> 16) & 1u)) >> 16);
}
__device__ __forceinline__ u32 pack2(float a, float b) {
  return (u32)f2bf(a) | ((u32)f2bf(b) << 16);
}

// ---------------- convert fp32 -> bf16 (contiguous) ----------------
__global__ __launch_bounds__(256) void cvt_bf16_kernel(const float* __restrict__ in,
                                                       u32* __restrict__ out, long n) {
  long i = ((long)blockIdx.x * 256 + threadIdx.x) * 8;
  if (i >= n) return;
  const float4* pf = (const float4*)(in + i);
  float4 f0 = pf[0], f1 = pf[1];
  uint4 o = make_uint4(pack2(f0.x, f0.y), pack2(f0.z, f0.w),
                       pack2(f1.x, f1.y), pack2(f1.z, f1.w));
  *(uint4*)(out + i / 2) = o;
}

// ------------- batched transpose + convert: in[z][R][C] f32 -> out[z][C][R] bf16 -------------
__global__ __launch_bounds__(256) void transpose_bf16_kernel(const float* __restrict__ in,
                                                             u16* __restrict__ out,
                                                             int R, int C) {
  __shared__ float tile[32][33];
  const size_t bo = (size_t)blockIdx.z * R * C;
  const int c0 = blockIdx.x * 32, r0 = blockIdx.y * 32;
  const int tx = threadIdx.x & 31, ty = threadIdx.x >> 5;   // 32 x 8
#pragma unroll
  for (int i = 0; i < 32; i += 8)
    tile[ty + i][tx] = in[bo + (size_t)(r0 + ty + i) * C + c0 + tx];
  __syncthreads();
#pragma unroll
  for (int i = 0; i < 32; i += 8)
    out[bo + (size_t)(c0 + ty + i) * R + r0 + tx] = f2bf(tile[tx][ty + i]);
}

// ---------------- MFMA GEMM, m97 structure ----------------
// C[m,n] (+)= sum_k A[m,k] * Bt[n,k]
// MODE 0: gating L1  : C = bf16( relu(acc + bias[n]) ),               grid (32,32,1)
// MODE 1: expert L1  : C = bf16( gate[m,e] * relu(acc + bias[e,n]) ), grid (32,32,E)
// MODE 2: final      : atomicAdd fp32 C += acc (split-K over z),      grid (32,8,4)
// __launch_bounds__(256,4): 4 blocks/CU -> grid 1024 is ONE tail-free co-resident
// round (VGPR 56 arch + 64 AGPR = 120 <= 128 budget; LDS 16KB*4 = 64KB <= 160KB).
template<int MODE>
__global__ __launch_bounds__(256, 4) void gemm_mfma(
    const bf16* __restrict__ A,
    const bf16* __restrict__ Bt,
    const float* __restrict__ bias,
    const float* __restrict__ gate,
    void* __restrict__ Cptr,
    int K, long ldB, long kOffB, long ldC, int kIters, int eArg)
{
  __shared__ __align__(16) bf16 smem[2 * 128 * 32];   // As | Bs, reused as epilogue scratch
  bf16* As = smem;
  bf16* Bs = smem + 128 * 32;

  const int tid  = threadIdx.x;
  const int wave = tid >> 6;
  const int lane = tid & 63;
  const int quad = lane >> 4;
  const int l16  = lane & 15;

  const int m0 = blockIdx.x * 128;
  const int n0 = blockIdx.y * 128;

  int expert = 0;
  long cColOff = 0;
  const bf16* Bp = Bt;
  const float* biasP = bias;
  if (MODE == 1) {
    if (gridDim.z > 1) { expert = blockIdx.z; cColOff = (long)expert * D_HID; }
    else               { expert = eArg; }
    Bp = Bt + (size_t)expert * D_HID * (size_t)ldB;
    biasP = bias + (size_t)expert * D_HID;
  }
  const long kBase = (MODE == 2) ? (long)blockIdx.z * kIters * 32 : 0;

  const int sRow = lane >> 2;
  const int sCol = (lane & 3) * 8;

  f32x4 acc[4][4];
#pragma unroll
  for (int i = 0; i < 4; ++i)
#pragma unroll
    for (int j = 0; j < 4; ++j)
      acc[i][j] = (f32x4){0.f, 0.f, 0.f, 0.f};

  const int wr = (wave >> 1) * 64;   // wave's 64x64 quadrant
  const int wc = (wave & 1) * 64;

  const bf16* aBase = A  + (size_t)(m0 + wave * 32 + sRow) * K   + kBase + sCol;
  const bf16* bBase = Bp + (size_t)(n0 + wave * 32 + sRow) * ldB + kOffB + kBase + sCol;
  bf16* asDst = As + (wave * 32) * 32;
  bf16* bsDst = Bs + (wave * 32) * 32;

  for (int kk = 0; kk < kIters; ++kk) {
    const long ko = (long)kk * 32;
#pragma unroll
    for (int s = 0; s < 2; ++s) {
      __builtin_amdgcn_global_load_lds(
          (__attribute__((address_space(1))) void*)(aBase + (size_t)(s * 16) * K + ko),
          (__attribute__((address_space(3))) void*)(asDst + s * 16 * 32), 16, 0, 0);
      __builtin_amdgcn_global_load_lds(
          (__attribute__((address_space(1))) void*)(bBase + (size_t)(s * 16) * ldB + ko),
          (__attribute__((address_space(3))) void*)(bsDst + s * 16 * 32), 16, 0, 0);
    }
    __syncthreads();
    bf16x8 af[4], bfv[4];
#pragma unroll
    for (int i = 0; i < 4; ++i) {
      af[i]  = *(const bf16x8*)(As + (wr + i * 16 + l16) * 32 + quad * 8);
      bfv[i] = *(const bf16x8*)(Bs + (wc + i * 16 + l16) * 32 + quad * 8);
    }
#pragma unroll
    for (int i = 0; i < 4; ++i)
#pragma unroll
      for (int j = 0; j < 4; ++j)
        acc[i][j] = __builtin_amdgcn_mfma_f32_16x16x32_bf16(af[i], bfv[j], acc[i][j], 0, 0, 0);
    __syncthreads();
  }

  // epilogue: C/D layout col = lane&15, row = quad*4 + reg
  if (MODE <= 1) {
    // Per-wave LDS transpose of the 64x64 wave tile (16-row slabs) so global
    // stores are bf16x8 (16B) instead of scalar u16 stride-16.
    // Slab row stride 72 bf16 (=144B) breaks the 16-way b128 read conflict.
    const int SL = 72;
    u16* slab = (u16*)smem + wave * (16 * SL);   // 4 waves * 2304B = 9216B <= 16KB
    u16* C = (u16*)Cptr;
    float bv[4];
#pragma unroll
    for (int j = 0; j < 4; ++j) bv[j] = biasP[n0 + wc + j * 16 + l16];
#pragma unroll
    for (int i = 0; i < 4; ++i) {
#pragma unroll
      for (int r = 0; r < 4; ++r) {
        const int lrow = quad * 4 + r;
        float sc = 1.0f;
        if (MODE == 1) sc = gate[(size_t)(m0 + wr + i * 16 + lrow) * NE + expert];
#pragma unroll
        for (int j = 0; j < 4; ++j) {
          float v = fmaxf(acc[i][j][r] + bv[j], 0.0f) * sc;
          slab[lrow * SL + j * 16 + l16] = f2bf(v);
        }
      }
      const int rrow = lane & 15;
      const int c0c  = lane >> 4;   // chunks c0c and c0c+4 of 8 per row
      bf16x8 v0 = *(const bf16x8*)(slab + rrow * SL + c0c * 8);
      bf16x8 v1 = *(const bf16x8*)(slab + rrow * SL + (c0c + 4) * 8);
      u16* orow = C + (size_t)(m0 + wr + i * 16 + rrow) * ldC + cColOff + n0 + wc;
      *(bf16x8*)(orow + c0c * 8)       = v0;
      *(bf16x8*)(orow + (c0c + 4) * 8) = v1;
    }
  } else {
    float* C = (float*)Cptr;
#pragma unroll
    for (int i = 0; i < 4; ++i) {
#pragma unroll
      for (int r = 0; r < 4; ++r) {
        const int row = m0 + wr + i * 16 + quad * 4 + r;
        float* crow = C + (size_t)row * ldC + n0 + wc + l16;
#pragma unroll
        for (int j = 0; j < 4; ++j)
          atomicAdd(crow + j * 16, acc[i][j][r]);
      }
    }
  }
}

// ---------------- gating layer 2 + softmax: one wave per row ----------------
__global__ __launch_bounds__(256) void gate_softmax_kernel(const bf16* __restrict__ g,
                                                           const float* __restrict__ Wg2,
                                                           const float* __restrict__ bg2,
                                                           float* __restrict__ gate) {
  const int wave = threadIdx.x >> 6, lane = threadIdx.x & 63;
  const int row = blockIdx.x * 4 + wave;
  const bf16* gr = g + (size_t)row * D_HID;
  float acc[NE];
#pragma unroll
  for (int e = 0; e < NE; ++e) acc[e] = 0.f;
  for (int k = lane; k < D_HID; k += 64) {
    const float gv = (float)gr[k];
    const float* w = Wg2 + (size_t)k * NE;
#pragma unroll
    for (int e = 0; e < NE; ++e) acc[e] += gv * w[e];
  }
#pragma unroll
  for (int e = 0; e < NE; ++e) {
    float v = acc[e];
#pragma unroll
    for (int off = 32; off > 0; off >>= 1) v += __shfl_down(v, off);
    acc[e] = v;
  }
  if (lane == 0) {
    float mx = -3.4e38f;
#pragma unroll
    for (int e = 0; e < NE; ++e) { acc[e] += bg2[e]; mx = fmaxf(mx, acc[e]); }
    float s = 0.f;
#pragma unroll
    for (int e = 0; e < NE; ++e) { acc[e] = __expf(acc[e] - mx); s += acc[e]; }
    const float inv = 1.f / s;
#pragma unroll
    for (int e = 0; e < NE; ++e) gate[(size_t)row * NE + e] = acc[e] * inv;
  }
}

// ---------------- out = sum_e gate[b,e] * b2[e,o]  (WRITES out, no memset needed) -------------
__global__ __launch_bounds__(256) void gate_bias_kernel(const float* __restrict__ gate,
                                                        const float* __restrict__ b2,
                                                        float* __restrict__ out) {
  const int idx = blockIdx.x * 256 + threadIdx.x;
  const int b = idx >> 8;            // D_OUT/4 = 256 float4 per row
  const int o = (idx & 255) * 4;
  float4 v = {0.f, 0.f, 0.f, 0.f};
#pragma unroll
  for (int e = 0; e < NE; ++e) {
    const float gv = gate[(size_t)b * NE + e];
    const float4 bb = *(const float4*)(b2 + (size_t)e * D_OUT + o);
    v.x += gv * bb.x; v.y += gv * bb.y; v.z += gv * bb.z; v.w += gv * bb.w;
  }
  *(float4*)(out + (size_t)b * D_OUT + o) = v;
}

extern "C" void kernel_launch(void* const* d_in, const int* in_sizes, int n_in,
                              void* d_out, int out_size, void* d_ws, size_t ws_size,
                              hipStream_t stream) {
  const float* x   = (const float*)d_in[0];   // [4096,1024]
  const float* W1  = (const float*)d_in[1];   // [8,1024,4096]
  const float* b1  = (const float*)d_in[2];   // [8,4096]
  const float* W2  = (const float*)d_in[3];   // [8,4096,1024] == [32768,1024]
  const float* b2  = (const float*)d_in[4];   // [8,1024]
  const float* Wg1 = (const float*)d_in[5];   // [1024,4096]
  const float* bg1 = (const float*)d_in[6];   // [4096]
  const float* Wg2 = (const float*)d_in[7];   // [4096,8]
  const float* bg2 = (const float*)d_in[8];   // [8]
  float* out = (float*)d_out;                 // [4096,1024] fp32

  char* p = (char*)d_ws;
  bf16* xb   = (bf16*)p; p += (size_t)B_TOK * D_IN * 2;        //  8.4 MB
  bf16* Wg1t = (bf16*)p; p += (size_t)D_HID * D_IN * 2;        //  8.4 MB [4096,1024]
  bf16* W1t  = (bf16*)p; p += (size_t)NE * D_HID * D_IN * 2;   // 67 MB   [8][4096,1024]
  bf16* W2t  = (bf16*)p; p += (size_t)D_OUT * KTOT * 2;        // 67 MB   [1024,32768]
  bf16* g    = (bf16*)p; p += (size_t)B_TOK * D_HID * 2;       // 33.5 MB
  float* gate= (float*)p; p += (size_t)B_TOK * NE * 4;         //  0.13 MB
  bf16* hs   = (bf16*)p;                                       // big: 268 MB / small: 33.5 MB
  const size_t fixed = (size_t)(p - (char*)d_ws);
  const bool big = ws_size >= fixed + (size_t)B_TOK * KTOT * 2;

  // 1. convert x to bf16
  cvt_bf16_kernel<<<(B_TOK * D_IN / 8 + 255) / 256, 256, 0, stream>>>(x, (u32*)xb, (long)B_TOK * D_IN);
  // 2. transpose+convert weights to [N,K] bf16
  transpose_bf16_kernel<<<dim3(D_HID / 32, D_IN / 32, 1), 256, 0, stream>>>(Wg1, (u16*)Wg1t, D_IN, D_HID);
  transpose_bf16_kernel<<<dim3(D_HID / 32, D_IN / 32, NE), 256, 0, stream>>>(W1, (u16*)W1t, D_IN, D_HID);
  transpose_bf16_kernel<<<dim3(D_OUT / 32, KTOT / 32, 1), 256, 0, stream>>>(W2, (u16*)W2t, KTOT, D_OUT);
  // 3. gating L1: g = relu(xb @ Wg1t^T + bg1)   M=4096 N=4096 K=1024
  gemm_mfma<0><<<dim3(32, 32, 1), 256, 0, stream>>>(xb, Wg1t, bg1, nullptr, g,
                                                    D_IN, (long)D_IN, 0L, (long)D_HID, D_IN / 32, 0);
  // 4. gate = softmax(g @ Wg2 + bg2)
  gate_softmax_kernel<<<B_TOK / 4, 256, 0, stream>>>(g, Wg2, bg2, gate);
  // 5. out = sum_e gate*b2  (writes every element; atomics accumulate on top)
  gate_bias_kernel<<<B_TOK * D_OUT / 4 / 256, 256, 0, stream>>>(gate, b2, out);

  if (big) {
    // 6. hs[b, e*4096+j] = gate[b,e]*relu(xb @ W1t[e]^T + b1[e])  grid 8192 = 8 exact rounds
    gemm_mfma<1><<<dim3(32, 32, NE), 256, 0, stream>>>(xb, W1t, b1, gate, hs,
                                                       D_IN, (long)D_IN, 0L, (long)KTOT, D_IN / 32, 0);
    // 7. out += hs @ W2flat   M=4096 N=1024 K=32768, split-K=4: grid 1024 = ONE round
    gemm_mfma<2><<<dim3(32, 8, 4), 256, 0, stream>>>(hs, W2t, nullptr, nullptr, out,
                                                     KTOT, (long)KTOT, 0L, (long)D_OUT, KTOT / 4 / 32, 0);
  } else {
    for (int e = 0; e < NE; ++e) {
      gemm_mfma<1><<<dim3(32, 32, 1), 256, 0, stream>>>(xb, W1t, b1, gate, hs,
                                                        D_IN, (long)D_IN, 0L, (long)D_HID, D_IN / 32, e);
      gemm_mfma<2><<<dim3(32, 8, 2), 256, 0, stream>>>(hs, W2t, nullptr, nullptr, out,
                                                       D_HID, (long)KTOT, (long)e * D_HID, (long)D_OUT,
                                                       D_HID / 2 / 32, e);
    }
  }
}

// Round 3
// 1017.684 us; speedup vs baseline: 1.1103x; 1.1103x over previous
//
#include <hip/hip_runtime.h>
#include <stdint.h>

typedef __bf16 bf16;
typedef __attribute__((ext_vector_type(8))) __bf16 bf16x8;
typedef __attribute__((ext_vector_type(4))) float f32x4;
typedef unsigned short u16;
typedef unsigned int u32;

#define B_TOK 4096
#define D_IN  1024
#define D_HID 4096
#define D_OUT 1024
#define NE    8
#define KTOT  (NE * D_HID)   // 32768

// fp32 -> bf16 round-to-nearest-even
__device__ __forceinline__ u16 f2bf(float f) {
  u32 u = __float_as_uint(f);
  return (u16)((u + 0x7FFFu + ((u >> 16) & 1u)) >> 16);
}
__device__ __forceinline__ u32 pack2(float a, float b) {
  return (u32)f2bf(a) | ((u32)f2bf(b) << 16);
}

// ---------------- convert fp32 -> bf16 (contiguous) ----------------
__global__ __launch_bounds__(256) void cvt_bf16_kernel(const float* __restrict__ in,
                                                       u32* __restrict__ out, long n) {
  long i = ((long)blockIdx.x * 256 + threadIdx.x) * 8;
  if (i >= n) return;
  const float4* pf = (const float4*)(in + i);
  float4 f0 = pf[0], f1 = pf[1];
  uint4 o = make_uint4(pack2(f0.x, f0.y), pack2(f0.z, f0.w),
                       pack2(f1.x, f1.y), pack2(f1.z, f1.w));
  *(uint4*)(out + i / 2) = o;
}

// ------- batched transpose + convert: in[z][R][C] f32 -> out[z][C][R] bf16 -------
// 64x64 tiles; float4 coalesced loads, bf16x8 coalesced stores.
// LDS stride 68 u16 (=136B): write pattern 2-way bank alias (free), reads ~free.
__global__ __launch_bounds__(256) void transpose_bf16_kernel(const float* __restrict__ in,
                                                             u16* __restrict__ out,
                                                             int R, int C) {
  __shared__ u16 tileT[64][68];   // [col-of-in][row-of-in]
  const size_t bo = (size_t)blockIdx.z * R * C;
  const int c0 = blockIdx.x * 64, r0 = blockIdx.y * 64;
  const int tid = threadIdx.x;
  const int lr = tid >> 4;           // 0..15
  const int lc = (tid & 15) * 4;     // 0..60
#pragma unroll
  for (int p = 0; p < 4; ++p) {
    const int r = p * 16 + lr;
    const float4 v = *(const float4*)(in + bo + (size_t)(r0 + r) * C + c0 + lc);
    tileT[lc + 0][r] = f2bf(v.x);
    tileT[lc + 1][r] = f2bf(v.y);
    tileT[lc + 2][r] = f2bf(v.z);
    tileT[lc + 3][r] = f2bf(v.w);
  }
  __syncthreads();
  const int oc  = tid >> 3;          // 0..31
  const int och = (tid & 7) * 8;     // 0..56
#pragma unroll
  for (int p = 0; p < 2; ++p) {
    const int c = p * 32 + oc;
    bf16x8 v = *(const bf16x8*)(&tileT[c][och]);
    *(bf16x8*)(out + bo + (size_t)(c0 + c) * R + r0 + och) = v;
  }
}

// ---------------- MFMA GEMM, BK=64, XOR-swizzled LDS ----------------
// C[m,n] (+)= sum_k A[m,k] * Bt[n,k]
// MODE 0: gating L1  : C = bf16( relu(acc + bias[n]) ),               grid (32,32,1)
// MODE 1: expert L1  : C = bf16( gate[m,e] * relu(acc + bias[e,n]) ), grid (32,32,E)
// MODE 2: final      : atomicAdd fp32 C += acc (split-K over z),      grid (32,8,4)
// LDS 32KB/block -> 4 blocks/CU (128KB<=160KB). 32 MFMA per barrier-pair.
// Swizzle: LDS slot (row, chunk) holds global k-chunk (chunk ^ (row&7));
// folded into the staging lane->global map (global_load_lds LDS dst is lane*16 fixed).
template<int MODE>
__global__ __launch_bounds__(256, 4) void gemm_mfma(
    const bf16* __restrict__ A,
    const bf16* __restrict__ Bt,
    const float* __restrict__ bias,
    const float* __restrict__ gate,
    void* __restrict__ Cptr,
    int K, long ldB, long kOffB, long ldC, int kIters, int eArg)
{
  __shared__ __align__(16) bf16 smem[2 * 128 * 64];   // As | Bs = 32 KB
  bf16* As = smem;
  bf16* Bs = smem + 128 * 64;

  const int tid  = threadIdx.x;
  const int wave = tid >> 6;
  const int lane = tid & 63;
  const int quad = lane >> 4;
  const int l16  = lane & 15;

  const int m0 = blockIdx.x * 128;
  const int n0 = blockIdx.y * 128;

  int expert = 0;
  long cColOff = 0;
  const bf16* Bp = Bt;
  const float* biasP = bias;
  if (MODE == 1) {
    if (gridDim.z > 1) { expert = blockIdx.z; cColOff = (long)expert * D_HID; }
    else               { expert = eArg; }
    Bp = Bt + (size_t)expert * D_HID * (size_t)ldB;
    biasP = bias + (size_t)expert * D_HID;
  }
  const long kBase = (MODE == 2) ? (long)blockIdx.z * kIters * 64 : 0;

  // staging: inst s (0..3) covers rows wave*32 + s*8 + (lane>>3);
  // lane&7 picks the LDS chunk slot; global chunk = (lane&7) ^ (lane>>3).
  const int sRow = lane >> 3;                      // 0..7
  const int sCol = ((lane & 7) ^ sRow) * 8;        // XOR-swizzled global k-chunk

  f32x4 acc[4][4];
#pragma unroll
  for (int i = 0; i < 4; ++i)
#pragma unroll
    for (int j = 0; j < 4; ++j)
      acc[i][j] = (f32x4){0.f, 0.f, 0.f, 0.f};

  const int wr = (wave >> 1) * 64;   // wave's 64x64 quadrant
  const int wc = (wave & 1) * 64;

  const bf16* aBase = A  + (size_t)(m0 + wave * 32 + sRow) * K   + kBase + sCol;
  const bf16* bBase = Bp + (size_t)(n0 + wave * 32 + sRow) * ldB + kOffB + kBase + sCol;
  bf16* asDst = As + (wave * 32) * 64;
  bf16* bsDst = Bs + (wave * 32) * 64;

  for (int kk = 0; kk < kIters; ++kk) {
    const long ko = (long)kk * 64;
#pragma unroll
    for (int s = 0; s < 4; ++s) {
      __builtin_amdgcn_global_load_lds(
          (__attribute__((address_space(1))) void*)(aBase + (size_t)(s * 8) * K + ko),
          (__attribute__((address_space(3))) void*)(asDst + s * 8 * 64), 16, 0, 0);
      __builtin_amdgcn_global_load_lds(
          (__attribute__((address_space(1))) void*)(bBase + (size_t)(s * 8) * ldB + ko),
          (__attribute__((address_space(3))) void*)(bsDst + s * 8 * 64), 16, 0, 0);
    }
    __syncthreads();
#pragma unroll
    for (int t = 0; t < 2; ++t) {
      bf16x8 af[4], bfv[4];
      const int sw = (((t << 2) + quad) ^ (l16 & 7)) << 3;   // swizzled byte/2 offset
#pragma unroll
      for (int i = 0; i < 4; ++i) {
        af[i]  = *(const bf16x8*)(As + (wr + i * 16 + l16) * 64 + sw);
        bfv[i] = *(const bf16x8*)(Bs + (wc + i * 16 + l16) * 64 + sw);
      }
#pragma unroll
      for (int i = 0; i < 4; ++i)
#pragma unroll
        for (int j = 0; j < 4; ++j)
          acc[i][j] = __builtin_amdgcn_mfma_f32_16x16x32_bf16(af[i], bfv[j], acc[i][j], 0, 0, 0);
    }
    __syncthreads();
  }

  // epilogue: C/D layout col = lane&15, row = quad*4 + reg
  if (MODE <= 1) {
    // per-wave LDS transpose slab -> bf16x8 global stores
    const int SL = 72;
    u16* slab = (u16*)smem + wave * (16 * SL);
    u16* C = (u16*)Cptr;
    float bv[4];
#pragma unroll
    for (int j = 0; j < 4; ++j) bv[j] = biasP[n0 + wc + j * 16 + l16];
#pragma unroll
    for (int i = 0; i < 4; ++i) {
#pragma unroll
      for (int r = 0; r < 4; ++r) {
        const int lrow = quad * 4 + r;
        float sc = 1.0f;
        if (MODE == 1) sc = gate[(size_t)(m0 + wr + i * 16 + lrow) * NE + expert];
#pragma unroll
        for (int j = 0; j < 4; ++j) {
          float v = fmaxf(acc[i][j][r] + bv[j], 0.0f) * sc;
          slab[lrow * SL + j * 16 + l16] = f2bf(v);
        }
      }
      const int rrow = lane & 15;
      const int c0c  = lane >> 4;
      bf16x8 v0 = *(const bf16x8*)(slab + rrow * SL + c0c * 8);
      bf16x8 v1 = *(const bf16x8*)(slab + rrow * SL + (c0c + 4) * 8);
      u16* orow = C + (size_t)(m0 + wr + i * 16 + rrow) * ldC + cColOff + n0 + wc;
      *(bf16x8*)(orow + c0c * 8)       = v0;
      *(bf16x8*)(orow + (c0c + 4) * 8) = v1;
    }
  } else {
    float* C = (float*)Cptr;
#pragma unroll
    for (int i = 0; i < 4; ++i) {
#pragma unroll
      for (int r = 0; r < 4; ++r) {
        const int row = m0 + wr + i * 16 + quad * 4 + r;
        float* crow = C + (size_t)row * ldC + n0 + wc + l16;
#pragma unroll
        for (int j = 0; j < 4; ++j)
          atomicAdd(crow + j * 16, acc[i][j][r]);
      }
    }
  }
}

// ---------------- gating layer 2 + softmax: one wave per row ----------------
__global__ __launch_bounds__(256) void gate_softmax_kernel(const bf16* __restrict__ g,
                                                           const float* __restrict__ Wg2,
                                                           const float* __restrict__ bg2,
                                                           float* __restrict__ gate) {
  const int wave = threadIdx.x >> 6, lane = threadIdx.x & 63;
  const int row = blockIdx.x * 4 + wave;
  const bf16* gr = g + (size_t)row * D_HID;
  float acc[NE];
#pragma unroll
  for (int e = 0; e < NE; ++e) acc[e] = 0.f;
  for (int k = lane; k < D_HID; k += 64) {
    const float gv = (float)gr[k];
    const float* w = Wg2 + (size_t)k * NE;
#pragma unroll
    for (int e = 0; e < NE; ++e) acc[e] += gv * w[e];
  }
#pragma unroll
  for (int e = 0; e < NE; ++e) {
    float v = acc[e];
#pragma unroll
    for (int off = 32; off > 0; off >>= 1) v += __shfl_down(v, off);
    acc[e] = v;
  }
  if (lane == 0) {
    float mx = -3.4e38f;
#pragma unroll
    for (int e = 0; e < NE; ++e) { acc[e] += bg2[e]; mx = fmaxf(mx, acc[e]); }
    float s = 0.f;
#pragma unroll
    for (int e = 0; e < NE; ++e) { acc[e] = __expf(acc[e] - mx); s += acc[e]; }
    const float inv = 1.f / s;
#pragma unroll
    for (int e = 0; e < NE; ++e) gate[(size_t)row * NE + e] = acc[e] * inv;
  }
}

// ---------------- out = sum_e gate[b,e] * b2[e,o]  (WRITES out) -------------
__global__ __launch_bounds__(256) void gate_bias_kernel(const float* __restrict__ gate,
                                                        const float* __restrict__ b2,
                                                        float* __restrict__ out) {
  const int idx = blockIdx.x * 256 + threadIdx.x;
  const int b = idx >> 8;
  const int o = (idx & 255) * 4;
  float4 v = {0.f, 0.f, 0.f, 0.f};
#pragma unroll
  for (int e = 0; e < NE; ++e) {
    const float gv = gate[(size_t)b * NE + e];
    const float4 bb = *(const float4*)(b2 + (size_t)e * D_OUT + o);
    v.x += gv * bb.x; v.y += gv * bb.y; v.z += gv * bb.z; v.w += gv * bb.w;
  }
  *(float4*)(out + (size_t)b * D_OUT + o) = v;
}

extern "C" void kernel_launch(void* const* d_in, const int* in_sizes, int n_in,
                              void* d_out, int out_size, void* d_ws, size_t ws_size,
                              hipStream_t stream) {
  const float* x   = (const float*)d_in[0];   // [4096,1024]
  const float* W1  = (const float*)d_in[1];   // [8,1024,4096]
  const float* b1  = (const float*)d_in[2];   // [8,4096]
  const float* W2  = (const float*)d_in[3];   // [8,4096,1024] == [32768,1024]
  const float* b2  = (const float*)d_in[4];   // [8,1024]
  const float* Wg1 = (const float*)d_in[5];   // [1024,4096]
  const float* bg1 = (const float*)d_in[6];   // [4096]
  const float* Wg2 = (const float*)d_in[7];   // [4096,8]
  const float* bg2 = (const float*)d_in[8];   // [8]
  float* out = (float*)d_out;                 // [4096,1024] fp32

  char* p = (char*)d_ws;
  bf16* xb   = (bf16*)p; p += (size_t)B_TOK * D_IN * 2;        //  8.4 MB
  bf16* Wg1t = (bf16*)p; p += (size_t)D_HID * D_IN * 2;        //  8.4 MB [4096,1024]
  bf16* W1t  = (bf16*)p; p += (size_t)NE * D_HID * D_IN * 2;   // 67 MB   [8][4096,1024]
  bf16* W2t  = (bf16*)p; p += (size_t)D_OUT * KTOT * 2;        // 67 MB   [1024,32768]
  bf16* g    = (bf16*)p; p += (size_t)B_TOK * D_HID * 2;       // 33.5 MB
  float* gate= (float*)p; p += (size_t)B_TOK * NE * 4;         //  0.13 MB
  bf16* hs   = (bf16*)p;                                       // big: 268 MB / small: 33.5 MB
  const size_t fixed = (size_t)(p - (char*)d_ws);
  const bool big = ws_size >= fixed + (size_t)B_TOK * KTOT * 2;

  // 1. convert x to bf16
  cvt_bf16_kernel<<<(B_TOK * D_IN / 8 + 255) / 256, 256, 0, stream>>>(x, (u32*)xb, (long)B_TOK * D_IN);
  // 2. transpose+convert weights to [N,K] bf16 (64x64 tiles)
  transpose_bf16_kernel<<<dim3(D_HID / 64, D_IN / 64, 1), 256, 0, stream>>>(Wg1, (u16*)Wg1t, D_IN, D_HID);
  transpose_bf16_kernel<<<dim3(D_HID / 64, D_IN / 64, NE), 256, 0, stream>>>(W1, (u16*)W1t, D_IN, D_HID);
  transpose_bf16_kernel<<<dim3(D_OUT / 64, KTOT / 64, 1), 256, 0, stream>>>(W2, (u16*)W2t, KTOT, D_OUT);
  // 3. gating L1: g = relu(xb @ Wg1t^T + bg1)   M=4096 N=4096 K=1024
  gemm_mfma<0><<<dim3(32, 32, 1), 256, 0, stream>>>(xb, Wg1t, bg1, nullptr, g,
                                                    D_IN, (long)D_IN, 0L, (long)D_HID, D_IN / 64, 0);
  // 4. gate = softmax(g @ Wg2 + bg2)
  gate_softmax_kernel<<<B_TOK / 4, 256, 0, stream>>>(g, Wg2, bg2, gate);
  // 5. out = sum_e gate*b2
  gate_bias_kernel<<<B_TOK * D_OUT / 4 / 256, 256, 0, stream>>>(gate, b2, out);

  if (big) {
    // 6. hs[b, e*4096+j] = gate[b,e]*relu(xb @ W1t[e]^T + b1[e])  grid 8192 = 8 rounds
    gemm_mfma<1><<<dim3(32, 32, NE), 256, 0, stream>>>(xb, W1t, b1, gate, hs,
                                                       D_IN, (long)D_IN, 0L, (long)KTOT, D_IN / 64, 0);
    // 7. out += hs @ W2flat   M=4096 N=1024 K=32768, split-K=4: grid 1024 = one round
    gemm_mfma<2><<<dim3(32, 8, 4), 256, 0, stream>>>(hs, W2t, nullptr, nullptr, out,
                                                     KTOT, (long)KTOT, 0L, (long)D_OUT, KTOT / 4 / 64, 0);
  } else {
    for (int e = 0; e < NE; ++e) {
      gemm_mfma<1><<<dim3(32, 32, 1), 256, 0, stream>>>(xb, W1t, b1, gate, hs,
                                                        D_IN, (long)D_IN, 0L, (long)D_HID, D_IN / 64, e);
      gemm_mfma<2><<<dim3(32, 8, 2), 256, 0, stream>>>(hs, W2t, nullptr, nullptr, out,
                                                       D_HID, (long)KTOT, (long)e * D_HID, (long)D_OUT,
                                                       D_HID / 2 / 64, e);
    }
  }
}